// Round 6
// baseline (106.774 us; speedup 1.0000x reference)
//
#include <hip/hip_runtime.h>
#include <hip/hip_bf16.h>

#define SEQ 2048

typedef __attribute__((ext_vector_type(8))) short short8;
typedef __attribute__((ext_vector_type(4))) float f32x4;

__device__ __forceinline__ ushort f2b(float f) {
    union { __hip_bfloat16 h; ushort u; } cv;
    cv.h = __float2bfloat16(f);
    return cv.u;
}

__device__ __forceinline__ void async_copy16(const void* g, void* l) {
    __builtin_amdgcn_global_load_lds(
        (const __attribute__((address_space(1))) void*)g,
        (__attribute__((address_space(3))) void*)l, 16, 0, 0);
}

// ---------------------------------------------------------------------------
// prep: blocks 0..255 convert x -> bf16; blocks 256..1535 transpose+convert
// the five 512x512 weight matrices (tile 32x32 each).
// ---------------------------------------------------------------------------
__global__ __launch_bounds__(256)
void prep(const float* __restrict__ x,
          const float* __restrict__ Wq, const float* __restrict__ Wk,
          const float* __restrict__ Wv, const float* __restrict__ Wff1,
          const float* __restrict__ Wff2,
          ushort* __restrict__ xb, ushort* __restrict__ WT,
          ushort* __restrict__ W1T, ushort* __restrict__ W2T)
{
    const int b = blockIdx.x, tid = threadIdx.x;
    if (b < 256) {
        int t0 = b * 256 + tid;
        #pragma unroll
        for (int j = 0; j < 4; ++j) {
            int i = (t0 + j * 65536) * 4;
            float4 v = *(const float4*)(x + i);
            ushort4 o;
            o.x = f2b(v.x); o.y = f2b(v.y); o.z = f2b(v.z); o.w = f2b(v.w);
            *(ushort4*)(xb + i) = o;
        }
        return;
    }
    const int j = b - 256;               // 0..1279
    const int z = j >> 8, tile = j & 255;
    const float* W = (z == 0) ? Wq : (z == 1) ? Wk : (z == 2) ? Wv
                      : (z == 3) ? Wff1 : Wff2;
    ushort* T = (z == 0) ? WT : (z == 1) ? (WT + 262144)
                  : (z == 2) ? (WT + 524288) : (z == 3) ? W1T : W2T;
    __shared__ float tsh[32][33];
    const int n0 = (tile & 15) * 32, k0 = (tile >> 4) * 32;
    const int tx = tid & 31, ty = tid >> 5;
    for (int r = ty; r < 32; r += 8)
        tsh[r][tx] = W[(k0 + r) * 512 + n0 + tx];
    __syncthreads();
    for (int r = ty; r < 32; r += 8)
        T[(n0 + r) * 512 + k0 + tx] = f2b(tsh[tx][r]);
}

// ---------------------------------------------------------------------------
// QKV GEMM: 384 blocks, tile 128x64 (mt = b/24 -> 128 rows, nt = b%24).
// nt<16 -> Q/K into QKb [2048][1024]; nt>=16 -> V written pre-transposed
// into Vtg[h][r][f][u]. Dbuf LDS (48KB), XOR k-octet swizzle,
// global_load_lds x16 staging. Each wave owns a 32-row strip x 64 cols:
// 16 MFMA per wave per k-chunk (2x density of the 64x64 tile).
// ---------------------------------------------------------------------------
__global__ __launch_bounds__(256)
void qkv_gemm(const ushort* __restrict__ xb, const ushort* __restrict__ WT,
              ushort* __restrict__ QKb, ushort* __restrict__ Vtg)
{
    __shared__ __align__(16) ushort As[2][128][64];   // 32 KB
    __shared__ __align__(16) ushort Bs[2][64][64];    // 16 KB
    const int tid = threadIdx.x;
    const int wv = tid >> 6, lane = tid & 63;
    const int lane15 = lane & 15, quad = lane >> 4;
    const int srow = lane >> 3, soct = lane & 7;

    const int t = blockIdx.x;
    const int nt = t % 24, mt = t / 24;
    const int n0 = nt * 64, m0 = mt * 128;
    const ushort* Bt = WT + (size_t)n0 * 512;

    const f32x4 z4 = {0.f, 0.f, 0.f, 0.f};
    f32x4 acc[2][4];
    #pragma unroll
    for (int mi = 0; mi < 2; ++mi)
        #pragma unroll
        for (int ni = 0; ni < 4; ++ni) acc[mi][ni] = z4;

    auto stage = [&](int buf, int kc) {
        #pragma unroll
        for (int i = 0; i < 4; ++i) {              // A: 128 rows
            int r0 = (wv * 4 + i) * 8;
            int r  = r0 + srow;
            int g  = soct ^ (r & 7);
            async_copy16(xb + (size_t)(m0 + r) * 512 + kc * 64 + g * 8,
                         &As[buf][r0][0]);
        }
        #pragma unroll
        for (int i = 0; i < 2; ++i) {              // B: 64 rows
            int r0 = (wv * 2 + i) * 8;
            int r  = r0 + srow;
            int g  = soct ^ (r & 7);
            async_copy16(Bt + (size_t)r * 512 + kc * 64 + g * 8,
                         &Bs[buf][r0][0]);
        }
    };

    stage(0, 0);
    __syncthreads();
    for (int kc = 0; kc < 8; ++kc) {
        if (kc < 7) stage((kc + 1) & 1, kc + 1);
        const ushort* Ab = &As[kc & 1][0][0];
        const ushort* Bb = &Bs[kc & 1][0][0];
        #pragma unroll
        for (int ks = 0; ks < 2; ++ks) {
            const int oct = ((ks * 4 + quad) ^ (lane15 & 7)) * 8;
            short8 a[2], bb[4];
            #pragma unroll
            for (int mi = 0; mi < 2; ++mi)
                a[mi] = *(const short8*)&Ab[(wv * 32 + mi * 16 + lane15) * 64 + oct];
            #pragma unroll
            for (int ni = 0; ni < 4; ++ni)
                bb[ni] = *(const short8*)&Bb[(ni * 16 + lane15) * 64 + oct];
            #pragma unroll
            for (int mi = 0; mi < 2; ++mi)
                #pragma unroll
                for (int ni = 0; ni < 4; ++ni)
                    acc[mi][ni] = __builtin_amdgcn_mfma_f32_16x16x32_bf16(
                        a[mi], bb[ni], acc[mi][ni], 0, 0, 0);
        }
        __syncthreads();
    }

    if (nt < 16) {
        #pragma unroll
        for (int mi = 0; mi < 2; ++mi)
            #pragma unroll
            for (int ni = 0; ni < 4; ++ni)
                #pragma unroll
                for (int reg = 0; reg < 4; ++reg) {
                    int row = m0 + wv * 32 + mi * 16 + quad * 4 + reg;
                    int col = n0 + ni * 16 + lane15;
                    QKb[(size_t)row * 1024 + col] = f2b(acc[mi][ni][reg]);
                }
    } else {
        // V tile (128 rows x 64 f) -> transposed Vtg[h][r][f][u], LDS r-t
        const int h = nt - 16;
        ushort* Ct = &As[0][0][0];   // 16 KB, dead now
        #pragma unroll
        for (int mi = 0; mi < 2; ++mi)
            #pragma unroll
            for (int ni = 0; ni < 4; ++ni)
                #pragma unroll
                for (int reg = 0; reg < 4; ++reg) {
                    int row = wv * 32 + mi * 16 + quad * 4 + reg;   // 0..127
                    int col = ni * 16 + lane15;                      // 0..63
                    Ct[row * 64 + col] = f2b(acc[mi][ni][reg]);
                }
        __syncthreads();
        const int f = tid >> 2, rr = tid & 3;
        __align__(16) ushort tmp[32];
        #pragma unroll
        for (int ul = 0; ul < 32; ++ul)
            tmp[ul] = Ct[(4 * ul + rr) * 64 + f];
        size_t base = (((size_t)h * 4 + rr) * 64 + f) * 512 + (m0 >> 2);
        #pragma unroll
        for (int q = 0; q < 4; ++q)
            *(short8*)&Vtg[base + 8 * q] = *(short8*)&tmp[8 * q];
    }
}

// ---------------------------------------------------------------------------
// MFMA dilated sliding-window attention. Block (c,r,h); 32 queries s = s0+4i.
// ---------------------------------------------------------------------------
__global__ __launch_bounds__(256)
void attn(const ushort* __restrict__ QKb, const ushort* __restrict__ Vtg,
          float* __restrict__ X, ushort* __restrict__ Xb)
{
    const int c = blockIdx.x, r = blockIdx.y, h = blockIdx.z;
    const int tid = threadIdx.x;
    const int wv = tid >> 6, lane = tid & 63;
    const int lane15 = lane & 15, quad = lane >> 4;
    const int s0 = r + 128 * c;
    const int wm = wv & 1, nh = wv >> 1;

    __shared__ __align__(16) ushort Qs[32][64];     // 4 KB
    __shared__ __align__(16) ushort Ks[96][64];     // 12 KB
    __shared__ __align__(16) ushort Vts[64][128];   // 16 KB
    __shared__ __align__(16) ushort Ps[32][128];    // 8 KB
    __shared__ float psum[2][32];

    {   // stage Q
        int i = tid >> 3, o = tid & 7, g = o ^ (i & 7);
        *(short8*)&Qs[i][o * 8] =
            *(const short8*)&QKb[(size_t)(s0 + 4 * i) * 1024 + h * 64 + g * 8];
    }
    #pragma unroll
    for (int j = 0; j < 3; ++j) {   // stage K, zero-fill OOB
        int row = (tid >> 3) + 32 * j;
        int o = tid & 7, g = o ^ (row & 7);
        int p = s0 - 128 + 4 * row;
        short8 v = {0, 0, 0, 0, 0, 0, 0, 0};
        if (p >= 0 && p < SEQ)
            v = *(const short8*)&QKb[(size_t)p * 1024 + 512 + h * 64 + g * 8];
        *(short8*)&Ks[row][o * 8] = v;
    }
    {   // stage Vt window
        const int u0 = 32 * c - 32;
        const int f = tid & 63;
        #pragma unroll
        for (int j = 0; j < 3; ++j) {
            int o = (tid >> 6) + 4 * j;          // 0..11
            int u = u0 + 8 * o;
            short8 v = {0, 0, 0, 0, 0, 0, 0, 0};
            if (u >= 0 && u < 512)
                v = *(const short8*)&Vtg[(((size_t)h * 4 + r) * 64 + f) * 512 + u];
            *(short8*)&Vts[f][(o ^ (f & 7)) * 8] = v;
        }
    }
    __syncthreads();

    // QK
    const f32x4 z4 = {0.f, 0.f, 0.f, 0.f};
    f32x4 lacc[3];
    lacc[0] = z4; lacc[1] = z4; lacc[2] = z4;
    short8 qa[2];
    #pragma unroll
    for (int kt = 0; kt < 2; ++kt)
        qa[kt] = *(const short8*)
            &Qs[wm * 16 + lane15][((kt * 4 + quad) ^ (lane15 & 7)) * 8];
    #pragma unroll
    for (int tt = 0; tt < 3; ++tt) {
        int ntl = 3 * nh + tt;
        #pragma unroll
        for (int kt = 0; kt < 2; ++kt) {
            short8 kb = *(const short8*)
                &Ks[ntl * 16 + lane15][((kt * 4 + quad) ^ (lane15 & 7)) * 8];
            lacc[tt] = __builtin_amdgcn_mfma_f32_16x16x32_bf16(qa[kt], kb, lacc[tt], 0, 0, 0);
        }
    }

    // masked exp + partial row sums + unnormalized P (bf16)
    const int rowi = wm * 16 + quad * 4;
    float part[4] = {0.f, 0.f, 0.f, 0.f};
    #pragma unroll
    for (int tt = 0; tt < 3; ++tt) {
        int tcol = (3 * nh + tt) * 16 + lane15;
        #pragma unroll
        for (int reg = 0; reg < 4; ++reg) {
            int i = rowi + reg;
            int d = tcol - i;
            float e = 0.f;
            if (d >= 0 && d <= 64) e = __expf(lacc[tt][reg]);
            part[reg] += e;
            int ol = (tcol >> 3) ^ (i & 7);
            Ps[i][ol * 8 + (tcol & 7)] = f2b(e);
        }
    }
    #pragma unroll
    for (int reg = 0; reg < 4; ++reg) {
        float v = part[reg];
        v += __shfl_xor(v, 1);
        v += __shfl_xor(v, 2);
        v += __shfl_xor(v, 4);
        v += __shfl_xor(v, 8);
        part[reg] = v;
    }
    if (lane15 == 0) {
        #pragma unroll
        for (int reg = 0; reg < 4; ++reg)
            psum[nh][rowi + reg] = part[reg];
    }
    __syncthreads();

    // PV
    f32x4 oacc[2];
    oacc[0] = z4; oacc[1] = z4;
    short8 pa[3];
    #pragma unroll
    for (int kc = 0; kc < 3; ++kc)
        pa[kc] = *(const short8*)
            &Ps[wm * 16 + lane15][((kc * 4 + quad) ^ (lane15 & 7)) * 8];
    #pragma unroll
    for (int ft = 0; ft < 2; ++ft) {
        int fr = (2 * nh + ft) * 16 + lane15;
        #pragma unroll
        for (int kc = 0; kc < 3; ++kc) {
            short8 vb = *(const short8*)
                &Vts[fr][((kc * 4 + quad) ^ (fr & 7)) * 8];
            oacc[ft] = __builtin_amdgcn_mfma_f32_16x16x32_bf16(pa[kc], vb, oacc[ft], 0, 0, 0);
        }
    }

    #pragma unroll
    for (int reg = 0; reg < 4; ++reg) {
        int i = rowi + reg;
        float inv = 0.125f / (psum[0][i] + psum[1][i]);
        #pragma unroll
        for (int ft = 0; ft < 2; ++ft) {
            int f = (2 * nh + ft) * 16 + lane15;
            float v = oacc[ft][reg] * inv;
            size_t idx = (size_t)(s0 + 4 * i) * 512 + h * 64 + f;
            X[idx]  = v;
            Xb[idx] = f2b(v);
        }
    }
}

// ---------------------------------------------------------------------------
// FFN GEMM tile 64x64: 256 blocks, dbuf LDS (32KB), 4 waves in 32x32
// quadrants (8 MFMA per wave per k-chunk).
// ---------------------------------------------------------------------------
template<bool BIAS, bool RELU, bool ADDSRC, bool OUTBF16>
__global__ __launch_bounds__(256)
void ffn(const ushort* __restrict__ A, const ushort* __restrict__ BT,
         const float* __restrict__ bias, const float* __restrict__ addsrc,
         void* __restrict__ C)
{
    __shared__ __align__(16) ushort As[2][64][64];
    __shared__ __align__(16) ushort Bs[2][64][64];
    const int tid = threadIdx.x, b = blockIdx.x;
    const int wv = tid >> 6, lane = tid & 63;
    const int lane15 = lane & 15, quad = lane >> 4;
    const int srow = lane >> 3, soct = lane & 7;
    const int wm = wv & 1, wn = wv >> 1;
    const int n0 = (b & 7) * 64, m0 = (b >> 3) * 64;

    const f32x4 z4 = {0.f, 0.f, 0.f, 0.f};
    f32x4 acc[2][2];
    acc[0][0] = z4; acc[0][1] = z4; acc[1][0] = z4; acc[1][1] = z4;

    auto stage = [&](int buf, int kc) {
        #pragma unroll
        for (int i = 0; i < 2; ++i) {
            int r0 = (wv * 2 + i) * 8;
            int r  = r0 + srow;
            int g  = soct ^ (r & 7);
            async_copy16(A + (size_t)(m0 + r) * 512 + kc * 64 + g * 8,
                         &As[buf][r0][0]);
            async_copy16(BT + (size_t)(n0 + r) * 512 + kc * 64 + g * 8,
                         &Bs[buf][r0][0]);
        }
    };

    stage(0, 0);
    __syncthreads();
    for (int kc = 0; kc < 8; ++kc) {
        if (kc < 7) stage((kc + 1) & 1, kc + 1);
        const ushort* Ab = &As[kc & 1][0][0];
        const ushort* Bb = &Bs[kc & 1][0][0];
        #pragma unroll
        for (int ks = 0; ks < 2; ++ks) {
            const int oct = ((ks * 4 + quad) ^ (lane15 & 7)) * 8;
            short8 a[2], bb[2];
            #pragma unroll
            for (int mi = 0; mi < 2; ++mi)
                a[mi] = *(const short8*)&Ab[(wm * 32 + mi * 16 + lane15) * 64 + oct];
            #pragma unroll
            for (int ni = 0; ni < 2; ++ni)
                bb[ni] = *(const short8*)&Bb[(wn * 32 + ni * 16 + lane15) * 64 + oct];
            #pragma unroll
            for (int mi = 0; mi < 2; ++mi)
                #pragma unroll
                for (int ni = 0; ni < 2; ++ni)
                    acc[mi][ni] = __builtin_amdgcn_mfma_f32_16x16x32_bf16(
                        a[mi], bb[ni], acc[mi][ni], 0, 0, 0);
        }
        __syncthreads();
    }

    #pragma unroll
    for (int mi = 0; mi < 2; ++mi)
        #pragma unroll
        for (int ni = 0; ni < 2; ++ni)
            #pragma unroll
            for (int reg = 0; reg < 4; ++reg) {
                int row = m0 + wm * 32 + mi * 16 + quad * 4 + reg;
                int col = n0 + wn * 32 + ni * 16 + lane15;
                float v = acc[mi][ni][reg];
                if (BIAS) v += bias[col];
                if (RELU) v = fmaxf(v, 0.f);
                if (ADDSRC) v += addsrc[(size_t)row * 512 + col];
                if (OUTBF16) ((ushort*)C)[(size_t)row * 512 + col] = f2b(v);
                else         ((float*)C)[(size_t)row * 512 + col]  = v;
            }
}

// ---------------------------------------------------------------------------
extern "C" void kernel_launch(void* const* d_in, const int* in_sizes, int n_in,
                              void* d_out, int out_size, void* d_ws, size_t ws_size,
                              hipStream_t stream)
{
    const float* x    = (const float*)d_in[0];
    const float* Wq   = (const float*)d_in[1];
    const float* Wk   = (const float*)d_in[2];
    const float* Wv   = (const float*)d_in[3];
    const float* Wff1 = (const float*)d_in[4];
    const float* bff1 = (const float*)d_in[5];
    const float* Wff2 = (const float*)d_in[6];
    const float* bff2 = (const float*)d_in[7];
    float* out = (float*)d_out;

    char* w = (char*)d_ws;
    ushort* xb  = (ushort*)(w);                   // 2 MB   [2048][512]
    ushort* WT  = (ushort*)(w + (2ull  << 20));   // 1.5 MB [1536][512]
    ushort* W1T = (ushort*)(w + (3584ull << 10)); // 0.5 MB
    ushort* W2T = (ushort*)(w + (4ull  << 20));   // 0.5 MB
    ushort* QKb = (ushort*)(w + (5ull  << 20));   // 4 MB   [2048][1024]
    ushort* Vtg = (ushort*)(w + (9ull  << 20));   // 2 MB   [8][4][64][512]
    float*  X   = (float*) (w + (11ull << 20));   // 4 MB   [2048][512]
    ushort* Xb  = (ushort*)(w + (15ull << 20));   // 2 MB
    ushort* Fb  = (ushort*)(w + (17ull << 20));   // 2 MB

    prep<<<1536, 256, 0, stream>>>(x, Wq, Wk, Wv, Wff1, Wff2, xb, WT, W1T, W2T);
    qkv_gemm<<<384, 256, 0, stream>>>(xb, WT, QKb, Vtg);
    attn<<<dim3(16, 4, 8), 256, 0, stream>>>(QKb, Vtg, X, Xb);
    ffn<true, true, false, true><<<256, 256, 0, stream>>>(Xb, W1T, bff1, nullptr, Fb);
    ffn<true, true, true, false><<<256, 256, 0, stream>>>(Fb, W2T, bff2, X, out);
}

// Round 7
// 100.185 us; speedup vs baseline: 1.0658x; 1.0658x over previous
//
#include <hip/hip_runtime.h>
#include <hip/hip_bf16.h>

#define SEQ 2048

typedef __attribute__((ext_vector_type(8))) short short8;
typedef __attribute__((ext_vector_type(4))) float f32x4;

__device__ __forceinline__ ushort f2b(float f) {
    union { __hip_bfloat16 h; ushort u; } cv;
    cv.h = __float2bfloat16(f);
    return cv.u;
}

__device__ __forceinline__ float b2f(ushort u) {
    union { float f; unsigned v; } cv;
    cv.v = ((unsigned)u) << 16;
    return cv.f;
}

__device__ __forceinline__ void async_copy16(const void* g, void* l) {
    __builtin_amdgcn_global_load_lds(
        (const __attribute__((address_space(1))) void*)g,
        (__attribute__((address_space(3))) void*)l, 16, 0, 0);
}

// ---------------------------------------------------------------------------
// prep: blocks 0..255 convert x -> bf16; blocks 256..1535 transpose+convert
// the five 512x512 weight matrices (tile 32x32 each).
// ---------------------------------------------------------------------------
__global__ __launch_bounds__(256)
void prep(const float* __restrict__ x,
          const float* __restrict__ Wq, const float* __restrict__ Wk,
          const float* __restrict__ Wv, const float* __restrict__ Wff1,
          const float* __restrict__ Wff2,
          ushort* __restrict__ xb, ushort* __restrict__ WT,
          ushort* __restrict__ W1T, ushort* __restrict__ W2T)
{
    const int b = blockIdx.x, tid = threadIdx.x;
    if (b < 256) {
        int t0 = b * 256 + tid;
        #pragma unroll
        for (int j = 0; j < 4; ++j) {
            int i = (t0 + j * 65536) * 4;
            float4 v = *(const float4*)(x + i);
            ushort4 o;
            o.x = f2b(v.x); o.y = f2b(v.y); o.z = f2b(v.z); o.w = f2b(v.w);
            *(ushort4*)(xb + i) = o;
        }
        return;
    }
    const int j = b - 256;               // 0..1279
    const int z = j >> 8, tile = j & 255;
    const float* W = (z == 0) ? Wq : (z == 1) ? Wk : (z == 2) ? Wv
                      : (z == 3) ? Wff1 : Wff2;
    ushort* T = (z == 0) ? WT : (z == 1) ? (WT + 262144)
                  : (z == 2) ? (WT + 524288) : (z == 3) ? W1T : W2T;
    __shared__ float tsh[32][33];
    const int n0 = (tile & 15) * 32, k0 = (tile >> 4) * 32;
    const int tx = tid & 31, ty = tid >> 5;
    for (int r = ty; r < 32; r += 8)
        tsh[r][tx] = W[(k0 + r) * 512 + n0 + tx];
    __syncthreads();
    for (int r = ty; r < 32; r += 8)
        T[(n0 + r) * 512 + k0 + tx] = f2b(tsh[tx][r]);
}

// ---------------------------------------------------------------------------
// QKV GEMM (R5 shape): 768 blocks, tile 64x64. nt<16 -> Q/K into QKb
// [2048][1024]; nt>=16 -> V written pre-transposed into Vtg[h][r][f][u].
// Dbuf LDS, XOR k-octet swizzle, global_load_lds x16 staging.
// ---------------------------------------------------------------------------
__global__ __launch_bounds__(256)
void qkv_gemm(const ushort* __restrict__ xb, const ushort* __restrict__ WT,
              ushort* __restrict__ QKb, ushort* __restrict__ Vtg)
{
    __shared__ __align__(16) ushort As[2][64][64];   // 16 KB
    __shared__ __align__(16) ushort Bs[2][64][64];   // 16 KB
    const int tid = threadIdx.x;
    const int wv = tid >> 6, lane = tid & 63;
    const int lane15 = lane & 15, quad = lane >> 4;
    const int srow = lane >> 3, soct = lane & 7;
    const int wm = wv & 1, wn = wv >> 1;

    const int t = blockIdx.x;
    const int nt = t % 24, mt = t / 24;
    const int n0 = nt * 64, m0 = mt * 64;
    const ushort* Bt = WT + (size_t)n0 * 512;

    const f32x4 z4 = {0.f, 0.f, 0.f, 0.f};
    f32x4 acc[2][2];
    acc[0][0] = z4; acc[0][1] = z4; acc[1][0] = z4; acc[1][1] = z4;

    auto stage = [&](int buf, int kc) {
        #pragma unroll
        for (int half = 0; half < 2; ++half) {
            int r0 = wv * 16 + half * 8;
            int r  = r0 + srow;
            int g  = soct ^ (r & 7);
            async_copy16(xb + (size_t)(m0 + r) * 512 + kc * 64 + g * 8,
                         &As[buf][r0][0]);
            async_copy16(Bt + (size_t)r * 512 + kc * 64 + g * 8,
                         &Bs[buf][r0][0]);
        }
    };

    stage(0, 0);
    __syncthreads();
    for (int kc = 0; kc < 8; ++kc) {
        if (kc < 7) stage((kc + 1) & 1, kc + 1);
        const ushort* Ab = &As[kc & 1][0][0];
        const ushort* Bb = &Bs[kc & 1][0][0];
        #pragma unroll
        for (int ks = 0; ks < 2; ++ks) {
            const int oct = ((ks * 4 + quad) ^ (lane15 & 7)) * 8;
            short8 a[2], bb[2];
            #pragma unroll
            for (int mi = 0; mi < 2; ++mi)
                a[mi] = *(const short8*)&Ab[(wm * 32 + mi * 16 + lane15) * 64 + oct];
            #pragma unroll
            for (int ni = 0; ni < 2; ++ni)
                bb[ni] = *(const short8*)&Bb[(wn * 32 + ni * 16 + lane15) * 64 + oct];
            #pragma unroll
            for (int mi = 0; mi < 2; ++mi)
                #pragma unroll
                for (int ni = 0; ni < 2; ++ni)
                    acc[mi][ni] = __builtin_amdgcn_mfma_f32_16x16x32_bf16(
                        a[mi], bb[ni], acc[mi][ni], 0, 0, 0);
        }
        __syncthreads();
    }

    if (nt < 16) {
        #pragma unroll
        for (int mi = 0; mi < 2; ++mi)
            #pragma unroll
            for (int ni = 0; ni < 2; ++ni)
                #pragma unroll
                for (int reg = 0; reg < 4; ++reg) {
                    int row = m0 + wm * 32 + mi * 16 + quad * 4 + reg;
                    int col = n0 + wn * 32 + ni * 16 + lane15;
                    QKb[(size_t)row * 1024 + col] = f2b(acc[mi][ni][reg]);
                }
    } else {
        // V tile -> transposed Vtg[h][r][f][u] via LDS round-trip
        const int h = nt - 16;
        ushort* Ct = &As[0][0][0];   // 8 KB, dead now
        #pragma unroll
        for (int mi = 0; mi < 2; ++mi)
            #pragma unroll
            for (int ni = 0; ni < 2; ++ni)
                #pragma unroll
                for (int reg = 0; reg < 4; ++reg) {
                    int row = wm * 32 + mi * 16 + quad * 4 + reg;
                    int col = wn * 32 + ni * 16 + lane15;
                    Ct[row * 64 + col] = f2b(acc[mi][ni][reg]);
                }
        __syncthreads();
        const int rr = wv, f = lane;   // wave rr handles residue rr
        __align__(16) ushort tmp[16];
        #pragma unroll
        for (int ul = 0; ul < 16; ++ul)
            tmp[ul] = Ct[(4 * ul + rr) * 64 + f];
        size_t base = (((size_t)h * 4 + rr) * 64 + f) * 512 + (m0 >> 2);
        *(short8*)&Vtg[base]     = *(short8*)&tmp[0];
        *(short8*)&Vtg[base + 8] = *(short8*)&tmp[8];
    }
}

// ---------------------------------------------------------------------------
// MFMA dilated sliding-window attention. Block (c,r,h); 32 queries s = s0+4i.
// Writes bf16 Xb only (residual + FFN input both read bf16).
// ---------------------------------------------------------------------------
__global__ __launch_bounds__(256)
void attn(const ushort* __restrict__ QKb, const ushort* __restrict__ Vtg,
          ushort* __restrict__ Xb)
{
    const int c = blockIdx.x, r = blockIdx.y, h = blockIdx.z;
    const int tid = threadIdx.x;
    const int wv = tid >> 6, lane = tid & 63;
    const int lane15 = lane & 15, quad = lane >> 4;
    const int s0 = r + 128 * c;
    const int wm = wv & 1, nh = wv >> 1;

    __shared__ __align__(16) ushort Qs[32][64];     // 4 KB
    __shared__ __align__(16) ushort Ks[96][64];     // 12 KB
    __shared__ __align__(16) ushort Vts[64][128];   // 16 KB
    __shared__ __align__(16) ushort Ps[32][128];    // 8 KB
    __shared__ float psum[2][32];

    {   // stage Q
        int i = tid >> 3, o = tid & 7, g = o ^ (i & 7);
        *(short8*)&Qs[i][o * 8] =
            *(const short8*)&QKb[(size_t)(s0 + 4 * i) * 1024 + h * 64 + g * 8];
    }
    #pragma unroll
    for (int j = 0; j < 3; ++j) {   // stage K, zero-fill OOB
        int row = (tid >> 3) + 32 * j;
        int o = tid & 7, g = o ^ (row & 7);
        int p = s0 - 128 + 4 * row;
        short8 v = {0, 0, 0, 0, 0, 0, 0, 0};
        if (p >= 0 && p < SEQ)
            v = *(const short8*)&QKb[(size_t)p * 1024 + 512 + h * 64 + g * 8];
        *(short8*)&Ks[row][o * 8] = v;
    }
    {   // stage Vt window
        const int u0 = 32 * c - 32;
        const int f = tid & 63;
        #pragma unroll
        for (int j = 0; j < 3; ++j) {
            int o = (tid >> 6) + 4 * j;          // 0..11
            int u = u0 + 8 * o;
            short8 v = {0, 0, 0, 0, 0, 0, 0, 0};
            if (u >= 0 && u < 512)
                v = *(const short8*)&Vtg[(((size_t)h * 4 + r) * 64 + f) * 512 + u];
            *(short8*)&Vts[f][(o ^ (f & 7)) * 8] = v;
        }
    }
    __syncthreads();

    // QK
    const f32x4 z4 = {0.f, 0.f, 0.f, 0.f};
    f32x4 lacc[3];
    lacc[0] = z4; lacc[1] = z4; lacc[2] = z4;
    short8 qa[2];
    #pragma unroll
    for (int kt = 0; kt < 2; ++kt)
        qa[kt] = *(const short8*)
            &Qs[wm * 16 + lane15][((kt * 4 + quad) ^ (lane15 & 7)) * 8];
    #pragma unroll
    for (int tt = 0; tt < 3; ++tt) {
        int ntl = 3 * nh + tt;
        #pragma unroll
        for (int kt = 0; kt < 2; ++kt) {
            short8 kb = *(const short8*)
                &Ks[ntl * 16 + lane15][((kt * 4 + quad) ^ (lane15 & 7)) * 8];
            lacc[tt] = __builtin_amdgcn_mfma_f32_16x16x32_bf16(qa[kt], kb, lacc[tt], 0, 0, 0);
        }
    }

    // masked exp + partial row sums + unnormalized P (bf16)
    const int rowi = wm * 16 + quad * 4;
    float part[4] = {0.f, 0.f, 0.f, 0.f};
    #pragma unroll
    for (int tt = 0; tt < 3; ++tt) {
        int tcol = (3 * nh + tt) * 16 + lane15;
        #pragma unroll
        for (int reg = 0; reg < 4; ++reg) {
            int i = rowi + reg;
            int d = tcol - i;
            float e = 0.f;
            if (d >= 0 && d <= 64) e = __expf(lacc[tt][reg]);
            part[reg] += e;
            int ol = (tcol >> 3) ^ (i & 7);
            Ps[i][ol * 8 + (tcol & 7)] = f2b(e);
        }
    }
    #pragma unroll
    for (int reg = 0; reg < 4; ++reg) {
        float v = part[reg];
        v += __shfl_xor(v, 1);
        v += __shfl_xor(v, 2);
        v += __shfl_xor(v, 4);
        v += __shfl_xor(v, 8);
        part[reg] = v;
    }
    if (lane15 == 0) {
        #pragma unroll
        for (int reg = 0; reg < 4; ++reg)
            psum[nh][rowi + reg] = part[reg];
    }
    __syncthreads();

    // PV
    f32x4 oacc[2];
    oacc[0] = z4; oacc[1] = z4;
    short8 pa[3];
    #pragma unroll
    for (int kc = 0; kc < 3; ++kc)
        pa[kc] = *(const short8*)
            &Ps[wm * 16 + lane15][((kc * 4 + quad) ^ (lane15 & 7)) * 8];
    #pragma unroll
    for (int ft = 0; ft < 2; ++ft) {
        int fr = (2 * nh + ft) * 16 + lane15;
        #pragma unroll
        for (int kc = 0; kc < 3; ++kc) {
            short8 vb = *(const short8*)
                &Vts[fr][((kc * 4 + quad) ^ (fr & 7)) * 8];
            oacc[ft] = __builtin_amdgcn_mfma_f32_16x16x32_bf16(pa[kc], vb, oacc[ft], 0, 0, 0);
        }
    }

    #pragma unroll
    for (int reg = 0; reg < 4; ++reg) {
        int i = rowi + reg;
        float inv = 0.125f / (psum[0][i] + psum[1][i]);
        #pragma unroll
        for (int ft = 0; ft < 2; ++ft) {
            int f = (2 * nh + ft) * 16 + lane15;
            float v = oacc[ft][reg] * inv;
            Xb[(size_t)(s0 + 4 * i) * 512 + h * 64 + f] = f2b(v);
        }
    }
}

// ---------------------------------------------------------------------------
// FFN GEMM tile 32x64 (R5 shape): 512 blocks. Dbuf LDS, 4 waves, 16x32
// quadrants. Optional bf16 residual add (ADDSRC) from addsrc_bf.
// ---------------------------------------------------------------------------
template<bool BIAS, bool RELU, bool ADDSRC, bool OUTBF16>
__global__ __launch_bounds__(256)
void ffn(const ushort* __restrict__ A, const ushort* __restrict__ BT,
         const float* __restrict__ bias, const ushort* __restrict__ addsrc_bf,
         void* __restrict__ C)
{
    __shared__ __align__(16) char smem[24576];
    const int tid = threadIdx.x, b = blockIdx.x;
    const int wv = tid >> 6, lane = tid & 63;
    const int lane15 = lane & 15, quad = lane >> 4;
    const int srow = lane >> 3, soct = lane & 7;
    const int wm = wv & 1, wn = wv >> 1;
    const int n0 = (b & 7) * 64, m0 = (b >> 3) * 32;

    const f32x4 z4 = {0.f, 0.f, 0.f, 0.f};
    f32x4 acc[2] = {z4, z4};

    auto stage = [&](int buf, int kc) {
        {
            int r0 = wv * 8;
            int r  = r0 + srow;
            int g  = soct ^ (r & 7);
            async_copy16(A + (size_t)(m0 + r) * 512 + kc * 64 + g * 8,
                         smem + buf * 12288 + r0 * 128);
        }
        #pragma unroll
        for (int half = 0; half < 2; ++half) {
            int r0 = wv * 16 + half * 8;
            int r  = r0 + srow;
            int g  = soct ^ (r & 7);
            async_copy16(BT + (size_t)(n0 + r) * 512 + kc * 64 + g * 8,
                         smem + buf * 12288 + 4096 + r0 * 128);
        }
    };

    stage(0, 0);
    __syncthreads();
    for (int kc = 0; kc < 8; ++kc) {
        if (kc < 7) stage((kc + 1) & 1, kc + 1);
        const ushort* As = (const ushort*)(smem + (kc & 1) * 12288);
        const ushort* Bs = As + 2048;
        #pragma unroll
        for (int ks = 0; ks < 2; ++ks) {
            const int oct = ((ks * 4 + quad) ^ (lane15 & 7)) * 8;
            short8 a = *(const short8*)&As[(wm * 16 + lane15) * 64 + oct];
            #pragma unroll
            for (int ni = 0; ni < 2; ++ni) {
                short8 bb = *(const short8*)&Bs[(wn * 32 + ni * 16 + lane15) * 64 + oct];
                acc[ni] = __builtin_amdgcn_mfma_f32_16x16x32_bf16(a, bb, acc[ni], 0, 0, 0);
            }
        }
        __syncthreads();
    }

    #pragma unroll
    for (int ni = 0; ni < 2; ++ni)
        #pragma unroll
        for (int reg = 0; reg < 4; ++reg) {
            int row = m0 + wm * 16 + quad * 4 + reg;
            int col = n0 + wn * 32 + ni * 16 + lane15;
            float v = acc[ni][reg];
            if (BIAS) v += bias[col];
            if (RELU) v = fmaxf(v, 0.f);
            if (ADDSRC) v += b2f(addsrc_bf[(size_t)row * 512 + col]);
            if (OUTBF16) ((ushort*)C)[(size_t)row * 512 + col] = f2b(v);
            else         ((float*)C)[(size_t)row * 512 + col]  = v;
        }
}

// ---------------------------------------------------------------------------
extern "C" void kernel_launch(void* const* d_in, const int* in_sizes, int n_in,
                              void* d_out, int out_size, void* d_ws, size_t ws_size,
                              hipStream_t stream)
{
    const float* x    = (const float*)d_in[0];
    const float* Wq   = (const float*)d_in[1];
    const float* Wk   = (const float*)d_in[2];
    const float* Wv   = (const float*)d_in[3];
    const float* Wff1 = (const float*)d_in[4];
    const float* bff1 = (const float*)d_in[5];
    const float* Wff2 = (const float*)d_in[6];
    const float* bff2 = (const float*)d_in[7];
    float* out = (float*)d_out;

    char* w = (char*)d_ws;
    ushort* xb  = (ushort*)(w);                   // 2 MB   [2048][512]
    ushort* WT  = (ushort*)(w + (2ull  << 20));   // 1.5 MB [1536][512]
    ushort* W1T = (ushort*)(w + (3584ull << 10)); // 0.5 MB
    ushort* W2T = (ushort*)(w + (4ull  << 20));   // 0.5 MB
    ushort* QKb = (ushort*)(w + (5ull  << 20));   // 4 MB   [2048][1024]
    ushort* Vtg = (ushort*)(w + (9ull  << 20));   // 2 MB   [8][4][64][512]
    ushort* Xb  = (ushort*)(w + (11ull << 20));   // 2 MB   [2048][512]
    ushort* Fb  = (ushort*)(w + (13ull << 20));   // 2 MB

    prep<<<1536, 256, 0, stream>>>(x, Wq, Wk, Wv, Wff1, Wff2, xb, WT, W1T, W2T);
    qkv_gemm<<<768, 256, 0, stream>>>(xb, WT, QKb, Vtg);
    attn<<<dim3(16, 4, 8), 256, 0, stream>>>(QKb, Vtg, Xb);
    ffn<true, true, false, true><<<512, 256, 0, stream>>>(Xb, W1T, bff1, nullptr, Fb);
    ffn<true, true, true, false><<<512, 256, 0, stream>>>(Fb, W2T, bff2, Xb, out);
}